// Round 2
// baseline (98.423 us; speedup 1.0000x reference)
//
#include <hip/hip_runtime.h>

typedef int   int4v   __attribute__((ext_vector_type(4)));
typedef float float4v __attribute__((ext_vector_type(4)));

#define N_DIM 65536

__device__ __forceinline__ int quant8(float v) {
    int q = (int)rintf(v);           // round-half-to-even, matches jnp.round
    q = q > 127 ? 127 : q;
    q = q < -128 ? -128 : q;
    return q;
}

__device__ __forceinline__ unsigned int pack4(int q0, int q1, int q2, int q3) {
    return (unsigned int)((q0 & 0xff) | ((q1 & 0xff) << 8) |
                          ((q2 & 0xff) << 16) | ((q3 & 0xff) << 24));
}

// Pre-pass: w1/w2 are int-valued float32 in [-16,15]; pack to int8.
__global__ __launch_bounds__(256) void quant_weights(const float* __restrict__ w1,
                                                     const float* __restrict__ w2,
                                                     unsigned char* __restrict__ w1q,
                                                     unsigned char* __restrict__ w2q) {
    int idx = blockIdx.x * 256 + threadIdx.x;   // 32768 threads, 4 elems each
    const float* src;
    unsigned char* dst;
    int off;
    if (idx < 16384) { src = w1; dst = w1q; off = idx * 4; }
    else             { src = w2; dst = w2q; off = (idx - 16384) * 4; }
    float4v f = *reinterpret_cast<const float4v*>(src + off);
    unsigned int dw = pack4((int)f.x, (int)f.y, (int)f.z, (int)f.w);
    *reinterpret_cast<unsigned int*>(dst + off) = dw;
}

// Main fused kernel: one wave handles one 16-column tile.
__global__ __launch_bounds__(256) void qdq_main(const float* __restrict__ x,
                                                const unsigned char* __restrict__ w1q,
                                                const unsigned char* __restrict__ w2q,
                                                int* __restrict__ out) {
    __shared__ unsigned char pq[4][4096];   // per-wave prob_q buffer (16 cols x 256 k)

    const int tid  = threadIdx.x;
    const int wave = tid >> 6;
    const int lane = tid & 63;
    const int c    = lane & 15;     // column within tile / A row within row-tile
    const int g    = lane >> 4;     // k-group 0..3
    const int tile = blockIdx.x * 4 + wave;
    const int n0   = tile * 16;

    // ---- 1. Load + quantize x into GEMM1 B-fragments (registers only) ----
    // B frag (16x16x64): lane holds col c, k = kk*64 + g*16 + j (j=0..15 bytes)
    int4v bq[4];
    #pragma unroll
    for (int kk = 0; kk < 4; ++kk) {
        int q[16];
        #pragma unroll
        for (int j = 0; j < 16; ++j) {
            const int d = kk * 64 + g * 16 + j;
            float v = x[(size_t)d * N_DIM + n0 + c] * 16.0f;   // /INPUT_SCALE
            q[j] = quant8(v);
        }
        int4v b;
        b.x = (int)pack4(q[0],  q[1],  q[2],  q[3]);
        b.y = (int)pack4(q[4],  q[5],  q[6],  q[7]);
        b.z = (int)pack4(q[8],  q[9],  q[10], q[11]);
        b.w = (int)pack4(q[12], q[13], q[14], q[15]);
        bq[kk] = b;
    }

    // ---- 2. GEMM1: scores = w1q @ xq, clamp i16, dequant ----
    // A frag: lane reads w1 row (rt*16 + c), bytes kk*64 + g*16 .. +15
    float sc[64];   // scores for rows rt*16 + g*4 + r, column n0+c
    #pragma unroll
    for (int rt = 0; rt < 16; ++rt) {
        int4v acc = {0, 0, 0, 0};
        #pragma unroll
        for (int kk = 0; kk < 4; ++kk) {
            int4v a = *reinterpret_cast<const int4v*>(
                w1q + (rt * 16 + c) * 256 + kk * 64 + g * 16);
            acc = __builtin_amdgcn_mfma_i32_16x16x64_i8(a, bq[kk], acc, 0, 0, 0);
        }
        #pragma unroll
        for (int r = 0; r < 4; ++r) {
            int s = acc[r];
            s = s > 32767 ? 32767 : (s < -32768 ? -32768 : s);
            sc[rt * 4 + r] = (float)s * 0.00390625f;   // SCORE_SCALE
        }
    }

    // ---- 3. Softmax over k (256 rows of this column) ----
    // Lane holds 64 values; column's other 192 live in lanes c+16, c+32, c+48.
    float m = -1e30f;
    #pragma unroll
    for (int i = 0; i < 64; ++i) m = fmaxf(m, sc[i]);
    m = fmaxf(m, __shfl_xor(m, 16));
    m = fmaxf(m, __shfl_xor(m, 32));
    float sum = 0.0f;
    #pragma unroll
    for (int i = 0; i < 64; ++i) {
        sc[i] = expf(sc[i] - m);
        sum += sc[i];
    }
    sum += __shfl_xor(sum, 16);
    sum += __shfl_xor(sum, 32);
    const float qs = 2048.0f / sum;   // 1/PROB_SCALE / sum

    // ---- 4. Quantize probs, redistribute to GEMM2 B-frag layout via LDS ----
    // Lane holds k = rt*16 + g*4 + r for col c -> pack dword, swizzled write.
    unsigned char* buf = pq[wave];
    #pragma unroll
    for (int rt = 0; rt < 16; ++rt) {
        int q0 = quant8(sc[rt * 4 + 0] * qs);
        int q1 = quant8(sc[rt * 4 + 1] * qs);
        int q2 = quant8(sc[rt * 4 + 2] * qs);
        int q3 = quant8(sc[rt * 4 + 3] * qs);
        const int koff = rt * 16 + g * 4;
        *reinterpret_cast<unsigned int*>(buf + c * 256 + (koff ^ (c << 4))) =
            pack4(q0, q1, q2, q3);
    }
    __syncthreads();   // uniform across block; also fences LDS within wave

    // ---- 5. GEMM2: out = w2q @ q_probs ----
    int4v b2[4];
    #pragma unroll
    for (int kk = 0; kk < 4; ++kk) {
        const int koff = kk * 64 + g * 16;
        b2[kk] = *reinterpret_cast<const int4v*>(buf + c * 256 + (koff ^ (c << 4)));
    }
    #pragma unroll
    for (int rt = 0; rt < 16; ++rt) {
        int4v acc = {0, 0, 0, 0};
        #pragma unroll
        for (int kk = 0; kk < 4; ++kk) {
            int4v a = *reinterpret_cast<const int4v*>(
                w2q + (rt * 16 + c) * 256 + kk * 64 + g * 16);
            acc = __builtin_amdgcn_mfma_i32_16x16x64_i8(a, b2[kk], acc, 0, 0, 0);
        }
        #pragma unroll
        for (int r = 0; r < 4; ++r) {
            int s = acc[r];
            s = s > 32767 ? 32767 : (s < -32768 ? -32768 : s);
            out[(size_t)(rt * 16 + g * 4 + r) * N_DIM + n0 + c] = s;
        }
    }
}

extern "C" void kernel_launch(void* const* d_in, const int* in_sizes, int n_in,
                              void* d_out, int out_size, void* d_ws, size_t ws_size,
                              hipStream_t stream) {
    const float* x  = (const float*)d_in[0];
    const float* w1 = (const float*)d_in[1];
    const float* w2 = (const float*)d_in[2];
    int* out = (int*)d_out;

    unsigned char* w1q = (unsigned char*)d_ws;
    unsigned char* w2q = w1q + 65536;

    quant_weights<<<128, 256, 0, stream>>>(w1, w2, w1q, w2q);
    qdq_main<<<1024, 256, 0, stream>>>(x, w1q, w2q, out);
}

// Round 3
// 88.835 us; speedup vs baseline: 1.1079x; 1.1079x over previous
//
#include <hip/hip_runtime.h>

typedef int   int4v   __attribute__((ext_vector_type(4)));
typedef float float4v __attribute__((ext_vector_type(4)));

#define N_DIM 65536

__device__ __forceinline__ int quant8(float v) {
    int q = (int)rintf(v);           // round-half-to-even, matches jnp.round
    q = q > 127 ? 127 : q;
    q = q < -128 ? -128 : q;
    return q;
}

__device__ __forceinline__ int clamp16(int s) {
    s = s > 32767 ? 32767 : s;
    s = s < -32768 ? -32768 : s;
    return s;
}

// Pre-pass: w1/w2 are int-valued float32 in [-16,15]; pack to int8.
__global__ __launch_bounds__(256) void quant_weights(const float* __restrict__ w1,
                                                     const float* __restrict__ w2,
                                                     unsigned char* __restrict__ w1q,
                                                     unsigned char* __restrict__ w2q) {
    int idx = blockIdx.x * 256 + threadIdx.x;   // 32768 threads, 4 elems each
    const float* src;
    unsigned char* dst;
    int off;
    if (idx < 16384) { src = w1; dst = w1q; off = idx * 4; }
    else             { src = w2; dst = w2q; off = (idx - 16384) * 4; }
    float4v f = *reinterpret_cast<const float4v*>(src + off);
    unsigned int dw = (unsigned int)(((int)f.x & 0xff) | (((int)f.y & 0xff) << 8) |
                                     (((int)f.z & 0xff) << 16) | (((int)f.w & 0xff) << 24));
    *reinterpret_cast<unsigned int*>(dst + off) = dw;
}

// Main fused kernel: ONE WAVE per block, one 16-column tile per block.
__global__ __launch_bounds__(64, 4) void qdq_main(const float* __restrict__ x,
                                                  const unsigned char* __restrict__ w1q,
                                                  const unsigned char* __restrict__ w2q,
                                                  int* __restrict__ out) {
    __shared__ unsigned char xb[4096];   // quantized x tile, [n=16][d=256] bytes, swizzled
    __shared__ unsigned char pq[4096];   // quantized probs, [c=16][k=256] bytes, swizzled

    const int lane = threadIdx.x;   // 0..63
    const int c    = lane & 15;     // column within tile / A row within row-tile
    const int g    = lane >> 4;     // k-group 0..3
    const int n0   = blockIdx.x * 16;

    // ---- 1. Cooperative x stage: coalesced float4 loads + quantize + pack ----
    // lane covers row d = i*16 + dsub, cols n4*4 .. +3
    const int dsub = lane >> 2;     // 0..15
    const int n4   = lane & 3;      // 0..3
    const int R    = dsub & 3;      // row within transpose quad
    const int qb   = dsub & 12;     // quad base (d offset within 16-row group)

    unsigned int W[16];
    {
        const float* xp = x + (size_t)dsub * N_DIM + n0 + n4 * 4;
        #pragma unroll
        for (int i = 0; i < 16; ++i) {
            float4v v = *reinterpret_cast<const float4v*>(xp + (size_t)i * (16 * N_DIM));
            int q0 = quant8(v.x * 16.0f);
            int q1 = quant8(v.y * 16.0f);
            int q2 = quant8(v.z * 16.0f);
            int q3 = quant8(v.w * 16.0f);
            W[i] = (unsigned int)((q0 & 0xff) | ((q1 & 0xff) << 8) |
                                  ((q2 & 0xff) << 16) | ((q3 & 0xff) << 24));
        }
    }

    // ---- 2. In-register 4x4 byte transpose (lanes l, l^4, l^8, l^12) ----
    // After: lane holds bytes xq[dbase+0..3][n_t] (4 consecutive d at one n).
    const unsigned int sel1 = (R & 1) ? 0x03070206u : 0x05010400u;
    const unsigned int sel2 = (R & 2) ? 0x07060302u : 0x01000504u;
    const int colsel = (0x3120 >> (R * 4)) & 0xF;   // {0,2,1,3}[R]
    const int n_t = n4 * 4 + colsel;
    {
        #pragma unroll
        for (int i = 0; i < 16; ++i) {
            unsigned int t = (unsigned int)__shfl_xor((int)W[i], 4);
            unsigned int Q = __builtin_amdgcn_perm(t, W[i], sel1);
            unsigned int u = (unsigned int)__shfl_xor((int)Q, 8);
            unsigned int F = __builtin_amdgcn_perm(Q, u, sel2);
            const int dbase = i * 16 + qb;
            *reinterpret_cast<unsigned int*>(xb + n_t * 256 + (dbase ^ (n_t << 4))) = F;
        }
    }
    __syncthreads();

    // ---- 3. Read B-fragments for GEMM1 from LDS (conflict-free b128) ----
    int4v bq[4];
    #pragma unroll
    for (int kk = 0; kk < 4; ++kk) {
        bq[kk] = *reinterpret_cast<const int4v*>(
            xb + c * 256 + ((kk * 64 + g * 16) ^ (c << 4)));
    }

    // ---- 4. GEMM1 with A prefetch; scores packed as i16 pairs ----
    const unsigned char* a1base = w1q + c * 256 + g * 16;   // + rt*4096 + kk*64
    unsigned int sc16[32];
    int im = -(1 << 30);
    int4v a_cur[4];
    #pragma unroll
    for (int kk = 0; kk < 4; ++kk)
        a_cur[kk] = *reinterpret_cast<const int4v*>(a1base + kk * 64);
    #pragma unroll
    for (int rt = 0; rt < 16; ++rt) {
        int4v a_nxt[4];
        if (rt < 15) {
            #pragma unroll
            for (int kk = 0; kk < 4; ++kk)
                a_nxt[kk] = *reinterpret_cast<const int4v*>(
                    a1base + (rt + 1) * 4096 + kk * 64);
        }
        int4v acc = {0, 0, 0, 0};
        #pragma unroll
        for (int kk = 0; kk < 4; ++kk)
            acc = __builtin_amdgcn_mfma_i32_16x16x64_i8(a_cur[kk], bq[kk], acc, 0, 0, 0);
        const int s0 = clamp16(acc[0]);
        const int s1 = clamp16(acc[1]);
        const int s2 = clamp16(acc[2]);
        const int s3 = clamp16(acc[3]);
        int m01 = s0 > s1 ? s0 : s1;
        int m23 = s2 > s3 ? s2 : s3;
        int m = m01 > m23 ? m01 : m23;
        im = im > m ? im : m;
        sc16[2 * rt]     = (unsigned int)((s0 & 0xffff) | (s1 << 16));
        sc16[2 * rt + 1] = (unsigned int)((s2 & 0xffff) | (s3 << 16));
        #pragma unroll
        for (int kk = 0; kk < 4; ++kk) a_cur[kk] = a_nxt[kk];
    }

    // ---- 5. Softmax over k (int max, exp2 with folded scale) ----
    {
        int o = __shfl_xor(im, 16); im = im > o ? im : o;
        o = __shfl_xor(im, 32);     im = im > o ? im : o;
    }
    const float C = 0.0056355275034725134f;   // SCORE_SCALE * log2(e)
    float sum = 0.0f;
    #pragma unroll
    for (int i = 0; i < 32; ++i) {
        int lo = (int)(short)(sc16[i] & 0xffffu);
        int hi = (int)sc16[i] >> 16;
        sum += exp2f((float)(lo - im) * C);
        sum += exp2f((float)(hi - im) * C);
    }
    sum += __shfl_xor(sum, 16);
    sum += __shfl_xor(sum, 32);
    const float qs = 2048.0f / sum;   // (1/PROB_SCALE) / sum

    // ---- 6. Quantize probs (recompute exp2), pack into swizzled LDS ----
    #pragma unroll
    for (int rt = 0; rt < 16; ++rt) {
        int lo0 = (int)(short)(sc16[2 * rt] & 0xffffu);
        int hi0 = (int)sc16[2 * rt] >> 16;
        int lo1 = (int)(short)(sc16[2 * rt + 1] & 0xffffu);
        int hi1 = (int)sc16[2 * rt + 1] >> 16;
        int q0 = (int)rintf(exp2f((float)(lo0 - im) * C) * qs);
        int q1 = (int)rintf(exp2f((float)(hi0 - im) * C) * qs);
        int q2 = (int)rintf(exp2f((float)(lo1 - im) * C) * qs);
        int q3 = (int)rintf(exp2f((float)(hi1 - im) * C) * qs);
        q0 = q0 > 127 ? 127 : q0;
        q1 = q1 > 127 ? 127 : q1;
        q2 = q2 > 127 ? 127 : q2;
        q3 = q3 > 127 ? 127 : q3;
        const int koff = rt * 16 + g * 4;
        *reinterpret_cast<unsigned int*>(pq + c * 256 + (koff ^ (c << 4))) =
            (unsigned int)(q0 | (q1 << 8) | (q2 << 16) | (q3 << 24));
    }
    __syncthreads();

    // ---- 7. GEMM2: out = w2q @ q_probs, clamp i16, store int32 ----
    int4v b2[4];
    #pragma unroll
    for (int kk = 0; kk < 4; ++kk) {
        b2[kk] = *reinterpret_cast<const int4v*>(
            pq + c * 256 + ((kk * 64 + g * 16) ^ (c << 4)));
    }
    const unsigned char* a2base = w2q + c * 256 + g * 16;
    #pragma unroll
    for (int kk = 0; kk < 4; ++kk)
        a_cur[kk] = *reinterpret_cast<const int4v*>(a2base + kk * 64);
    #pragma unroll
    for (int rt = 0; rt < 16; ++rt) {
        int4v a_nxt[4];
        if (rt < 15) {
            #pragma unroll
            for (int kk = 0; kk < 4; ++kk)
                a_nxt[kk] = *reinterpret_cast<const int4v*>(
                    a2base + (rt + 1) * 4096 + kk * 64);
        }
        int4v acc = {0, 0, 0, 0};
        #pragma unroll
        for (int kk = 0; kk < 4; ++kk)
            acc = __builtin_amdgcn_mfma_i32_16x16x64_i8(a_cur[kk], b2[kk], acc, 0, 0, 0);
        #pragma unroll
        for (int r = 0; r < 4; ++r) {
            out[(size_t)(rt * 16 + g * 4 + r) * N_DIM + n0 + c] = clamp16(acc[r]);
        }
        #pragma unroll
        for (int kk = 0; kk < 4; ++kk) a_cur[kk] = a_nxt[kk];
    }
}

extern "C" void kernel_launch(void* const* d_in, const int* in_sizes, int n_in,
                              void* d_out, int out_size, void* d_ws, size_t ws_size,
                              hipStream_t stream) {
    const float* x  = (const float*)d_in[0];
    const float* w1 = (const float*)d_in[1];
    const float* w2 = (const float*)d_in[2];
    int* out = (int*)d_out;

    unsigned char* w1q = (unsigned char*)d_ws;
    unsigned char* w2q = w1q + 65536;

    quant_weights<<<128, 256, 0, stream>>>(w1, w2, w1q, w2q);
    qdq_main<<<4096, 64, 0, stream>>>(x, w1q, w2q, out);
}

// Round 4
// 54.224 us; speedup vs baseline: 1.8151x; 1.6383x over previous
//
#include <hip/hip_runtime.h>

typedef int   int4v   __attribute__((ext_vector_type(4)));
typedef float float4v __attribute__((ext_vector_type(4)));

#define N_DIM 65536

__device__ __forceinline__ int quant8(float v) {
    int q = (int)rintf(v);           // round-half-to-even, matches jnp.round
    q = q > 127 ? 127 : q;
    q = q < -128 ? -128 : q;
    return q;
}

__device__ __forceinline__ int clamp16(int s) {
    s = s > 32767 ? 32767 : s;
    s = s < -32768 ? -32768 : s;
    return s;
}

// Pre-pass: w1/w2 are int-valued float32 in [-16,15]; pack to int8.
__global__ __launch_bounds__(256) void quant_weights(const float* __restrict__ w1,
                                                     const float* __restrict__ w2,
                                                     unsigned char* __restrict__ w1q,
                                                     unsigned char* __restrict__ w2q) {
    int idx = blockIdx.x * 256 + threadIdx.x;   // 32768 threads, 4 elems each
    const float* src;
    unsigned char* dst;
    int off;
    if (idx < 16384) { src = w1; dst = w1q; off = idx * 4; }
    else             { src = w2; dst = w2q; off = (idx - 16384) * 4; }
    float4v f = *reinterpret_cast<const float4v*>(src + off);
    unsigned int dw = (unsigned int)(((int)f.x & 0xff) | (((int)f.y & 0xff) << 8) |
                                     (((int)f.z & 0xff) << 16) | (((int)f.w & 0xff) << 24));
    *reinterpret_cast<unsigned int*>(dst + off) = dw;
}

// Fused kernel: 4 waves/block; each wave owns a 32-column strip end-to-end.
// No __syncthreads anywhere — all LDS regions are wave-private.
__global__ __launch_bounds__(256, 2) void qdq_main(const float* __restrict__ x,
                                                   const unsigned char* __restrict__ w1q,
                                                   const unsigned char* __restrict__ w2q,
                                                   int* __restrict__ out) {
    __shared__ unsigned char xb[4][8192];   // per-wave: xq [32 n][256 d], swizzled
    __shared__ unsigned char pq[4][8192];   // per-wave: probs [32 n][256 k], swizzled

    const int tid  = threadIdx.x;
    const int wave = tid >> 6;
    const int lane = tid & 63;
    const int c    = lane & 15;     // MFMA col-in-tile / A row-in-rowtile
    const int g    = lane >> 4;     // MFMA k-group 0..3
    const int colbase = blockIdx.x * 128 + wave * 32;

    unsigned char* xw = xb[wave];
    unsigned char* pw = pq[wave];

    // ---- 1. Load + quantize x strip [256 d][32 n]: 128B-contiguous segments ----
    const int rsub = lane >> 3;     // 0..7: row within 8-row group
    const int cg   = lane & 7;      // col group: floats cg*4..+3
    unsigned int W[32];
    {
        const float* xp = x + (size_t)rsub * N_DIM + colbase + cg * 4;
        #pragma unroll
        for (int i = 0; i < 32; ++i) {
            float4v v = *reinterpret_cast<const float4v*>(xp + (size_t)i * (8 * N_DIM));
            int q0 = quant8(v.x * 16.0f);
            int q1 = quant8(v.y * 16.0f);
            int q2 = quant8(v.z * 16.0f);
            int q3 = quant8(v.w * 16.0f);
            W[i] = (unsigned int)((q0 & 0xff) | ((q1 & 0xff) << 8) |
                                  ((q2 & 0xff) << 16) | ((q3 & 0xff) << 24));
        }
    }

    // ---- 2. In-register 4x4 byte transpose (partners lane^8, lane^16) ----
    const int R = rsub & 3;
    const unsigned int sel1 = (R & 1) ? 0x03070206u : 0x05010400u;
    const unsigned int sel2 = (R & 2) ? 0x07060302u : 0x01000504u;
    const int colsel = (0x3120 >> (R * 4)) & 0xF;   // {0,2,1,3}[R]
    const int n_t = cg * 4 + colsel;                // wave-local col 0..31
    const int qb  = (lane >> 3) & 4;                // d-quad base within 8-row group
    #pragma unroll
    for (int i = 0; i < 32; ++i) {
        unsigned int t = (unsigned int)__shfl_xor((int)W[i], 8);
        unsigned int Q = __builtin_amdgcn_perm(t, W[i], sel1);
        unsigned int u = (unsigned int)__shfl_xor((int)Q, 16);
        unsigned int F = __builtin_amdgcn_perm(Q, u, sel2);
        const int dbase = i * 8 + qb;
        *reinterpret_cast<unsigned int*>(xw + n_t * 256 + (dbase ^ ((n_t & 15) << 4))) = F;
    }

    // ---- 3. B-fragments for GEMM1 (2 tiles x 4 k-chunks, b128 reads) ----
    int4v bq[2][4];
    #pragma unroll
    for (int t = 0; t < 2; ++t)
        #pragma unroll
        for (int kk = 0; kk < 4; ++kk)
            bq[t][kk] = *reinterpret_cast<const int4v*>(
                xw + (t * 16 + c) * 256 + ((kk * 64 + g * 16) ^ (c << 4)));

    // ---- 4. GEMM1: A shared across both tiles, prefetch one rt ahead ----
    const unsigned char* a1 = w1q + c * 256 + g * 16;
    unsigned int scA[32], scB[32];
    int imA = -(1 << 30), imB = -(1 << 30);
    int4v a_cur[4];
    #pragma unroll
    for (int kk = 0; kk < 4; ++kk)
        a_cur[kk] = *reinterpret_cast<const int4v*>(a1 + kk * 64);
    #pragma unroll
    for (int rt = 0; rt < 16; ++rt) {
        int4v a_nxt[4];
        if (rt < 15) {
            #pragma unroll
            for (int kk = 0; kk < 4; ++kk)
                a_nxt[kk] = *reinterpret_cast<const int4v*>(a1 + (rt + 1) * 4096 + kk * 64);
        }
        int4v accA = {0, 0, 0, 0}, accB = {0, 0, 0, 0};
        #pragma unroll
        for (int kk = 0; kk < 4; ++kk) {
            accA = __builtin_amdgcn_mfma_i32_16x16x64_i8(a_cur[kk], bq[0][kk], accA, 0, 0, 0);
            accB = __builtin_amdgcn_mfma_i32_16x16x64_i8(a_cur[kk], bq[1][kk], accB, 0, 0, 0);
        }
        {
            const int s0 = clamp16(accA[0]), s1 = clamp16(accA[1]);
            const int s2 = clamp16(accA[2]), s3 = clamp16(accA[3]);
            int m01 = s0 > s1 ? s0 : s1, m23 = s2 > s3 ? s2 : s3;
            int m = m01 > m23 ? m01 : m23;
            imA = imA > m ? imA : m;
            scA[2 * rt]     = (unsigned int)((s0 & 0xffff) | (s1 << 16));
            scA[2 * rt + 1] = (unsigned int)((s2 & 0xffff) | (s3 << 16));
        }
        {
            const int s0 = clamp16(accB[0]), s1 = clamp16(accB[1]);
            const int s2 = clamp16(accB[2]), s3 = clamp16(accB[3]);
            int m01 = s0 > s1 ? s0 : s1, m23 = s2 > s3 ? s2 : s3;
            int m = m01 > m23 ? m01 : m23;
            imB = imB > m ? imB : m;
            scB[2 * rt]     = (unsigned int)((s0 & 0xffff) | (s1 << 16));
            scB[2 * rt + 1] = (unsigned int)((s2 & 0xffff) | (s3 << 16));
        }
        #pragma unroll
        for (int kk = 0; kk < 4; ++kk) a_cur[kk] = a_nxt[kk];
    }

    // ---- 5. Softmax per tile (int max over 4-lane column group, exp2) ----
    const float C = 0.0056355275034725134f;   // SCORE_SCALE * log2(e)
    {
        int o = __shfl_xor(imA, 16); imA = imA > o ? imA : o;
        o = __shfl_xor(imA, 32);     imA = imA > o ? imA : o;
        o = __shfl_xor(imB, 16);     imB = imB > o ? imB : o;
        o = __shfl_xor(imB, 32);     imB = imB > o ? imB : o;
    }
    float sumA = 0.0f, sumB = 0.0f;
    #pragma unroll
    for (int i = 0; i < 32; ++i) {
        sumA += exp2f((float)((int)(short)(scA[i] & 0xffffu) - imA) * C);
        sumA += exp2f((float)((int)scA[i] >> 16) * C - (float)imA * C);
        sumB += exp2f((float)((int)(short)(scB[i] & 0xffffu) - imB) * C);
        sumB += exp2f((float)((int)scB[i] >> 16) * C - (float)imB * C);
    }
    // NOTE: keep the two exp2 argument forms consistent: recompute below uses (v-im)*C
    // (the second form above is algebraically identical in fp32 only if computed the
    // same way, so recompute both passes identically instead):
    sumA = 0.0f; sumB = 0.0f;
    #pragma unroll
    for (int i = 0; i < 32; ++i) {
        sumA += exp2f((float)((int)(short)(scA[i] & 0xffffu) - imA) * C);
        sumA += exp2f((float)(((int)scA[i] >> 16) - imA) * C);
        sumB += exp2f((float)((int)(short)(scB[i] & 0xffffu) - imB) * C);
        sumB += exp2f((float)(((int)scB[i] >> 16) - imB) * C);
    }
    sumA += __shfl_xor(sumA, 16); sumA += __shfl_xor(sumA, 32);
    sumB += __shfl_xor(sumB, 16); sumB += __shfl_xor(sumB, 32);
    const float qsA = 2048.0f / sumA;
    const float qsB = 2048.0f / sumB;

    // ---- 6. Quantize probs (recompute exp2), write wave-private swizzled LDS ----
    #pragma unroll
    for (int rt = 0; rt < 16; ++rt) {
        #pragma unroll
        for (int t = 0; t < 2; ++t) {
            const unsigned int w0 = t ? scB[2 * rt] : scA[2 * rt];
            const unsigned int w1 = t ? scB[2 * rt + 1] : scA[2 * rt + 1];
            const int im = t ? imB : imA;
            const float qs = t ? qsB : qsA;
            int q0 = (int)rintf(exp2f((float)((int)(short)(w0 & 0xffffu) - im) * C) * qs);
            int q1 = (int)rintf(exp2f((float)(((int)w0 >> 16) - im) * C) * qs);
            int q2 = (int)rintf(exp2f((float)((int)(short)(w1 & 0xffffu) - im) * C) * qs);
            int q3 = (int)rintf(exp2f((float)(((int)w1 >> 16) - im) * C) * qs);
            q0 = q0 > 127 ? 127 : q0;
            q1 = q1 > 127 ? 127 : q1;
            q2 = q2 > 127 ? 127 : q2;
            q3 = q3 > 127 ? 127 : q3;
            const int koff = rt * 16 + g * 4;
            *reinterpret_cast<unsigned int*>(
                pw + (t * 16 + c) * 256 + (koff ^ (c << 4))) =
                (unsigned int)(q0 | (q1 << 8) | (q2 << 16) | (q3 << 24));
        }
    }

    // ---- 7. GEMM2 (wave-private LDS -> frags; A prefetch; direct stores) ----
    int4v b2[2][4];
    #pragma unroll
    for (int t = 0; t < 2; ++t)
        #pragma unroll
        for (int kk = 0; kk < 4; ++kk)
            b2[t][kk] = *reinterpret_cast<const int4v*>(
                pw + (t * 16 + c) * 256 + ((kk * 64 + g * 16) ^ (c << 4)));

    const unsigned char* a2 = w2q + c * 256 + g * 16;
    #pragma unroll
    for (int kk = 0; kk < 4; ++kk)
        a_cur[kk] = *reinterpret_cast<const int4v*>(a2 + kk * 64);
    #pragma unroll
    for (int rt = 0; rt < 16; ++rt) {
        int4v a_nxt[4];
        if (rt < 15) {
            #pragma unroll
            for (int kk = 0; kk < 4; ++kk)
                a_nxt[kk] = *reinterpret_cast<const int4v*>(a2 + (rt + 1) * 4096 + kk * 64);
        }
        int4v accA = {0, 0, 0, 0}, accB = {0, 0, 0, 0};
        #pragma unroll
        for (int kk = 0; kk < 4; ++kk) {
            accA = __builtin_amdgcn_mfma_i32_16x16x64_i8(a_cur[kk], b2[0][kk], accA, 0, 0, 0);
            accB = __builtin_amdgcn_mfma_i32_16x16x64_i8(a_cur[kk], b2[1][kk], accB, 0, 0, 0);
        }
        #pragma unroll
        for (int r = 0; r < 4; ++r) {
            const size_t rowoff = (size_t)(rt * 16 + g * 4 + r) * N_DIM + colbase;
            out[rowoff + c]      = clamp16(accA[r]);
            out[rowoff + 16 + c] = clamp16(accB[r]);
        }
        #pragma unroll
        for (int kk = 0; kk < 4; ++kk) a_cur[kk] = a_nxt[kk];
    }
}

extern "C" void kernel_launch(void* const* d_in, const int* in_sizes, int n_in,
                              void* d_out, int out_size, void* d_ws, size_t ws_size,
                              hipStream_t stream) {
    const float* x  = (const float*)d_in[0];
    const float* w1 = (const float*)d_in[1];
    const float* w2 = (const float*)d_in[2];
    int* out = (int*)d_out;

    unsigned char* w1q = (unsigned char*)d_ws;
    unsigned char* w2q = w1q + 65536;

    quant_weights<<<128, 256, 0, stream>>>(w1, w2, w1q, w2q);
    qdq_main<<<512, 256, 0, stream>>>(x, w1q, w2q, out);
}